// Round 5
// baseline (69.344 us; speedup 1.0000x reference)
//
#include <hip/hip_runtime.h>

// out = F_amp(MLP(z_i, z_j, sep_xy2)) * (dxy / sep_r2)
// Packing is along the OUTPUT-NEURON axis: f32x2 = neurons (j, j+1).
// Weights are contiguous pairs -> uniform s_load -> SGPR pair used directly
// by v_pk_fma_f32 (no splat movs). Only activations are splatted (23/elem),
// hoisted out of the neuron-pair loop.

typedef float f32x4 __attribute__((ext_vector_type(4)));
typedef float f32x2 __attribute__((ext_vector_type(2)));

__device__ __forceinline__ f32x2 fma2(f32x2 a, f32x2 b, f32x2 c) {
    return __builtin_elementwise_fma(a, b, c);
}

__device__ __forceinline__ f32x2 lrelu2(f32x2 x) {
    return __builtin_elementwise_max(x, x * 0.1f);   // alpha=0.1
}

__device__ __forceinline__ float tanh_fast(float x) {
    // tanh(x) = 1 - 2/(exp(2x)+1); v_exp + v_rcp, exact limits at +-inf
    float e = __expf(2.0f * x);
    return 1.0f - 2.0f * __builtin_amdgcn_rcpf(e + 1.0f);
}

__device__ __forceinline__ f32x2 ldpair(const float* __restrict__ p) {
    return *reinterpret_cast<const f32x2*>(p);       // uniform -> SGPR pair
}

__global__ void __launch_bounds__(256) fused_mlp_kernel(
    const float* __restrict__ in,
    const float* __restrict__ W1, const float* __restrict__ b1,
    const float* __restrict__ W2, const float* __restrict__ b2,
    const float* __restrict__ W3, const float* __restrict__ b3,
    const float* __restrict__ W4, const float* __restrict__ b4,
    float* __restrict__ out, int npairs)
{
    int p = blockIdx.x * blockDim.x + threadIdx.x;
    if (p >= npairs) return;

    const f32x4* in4 = reinterpret_cast<const f32x4*>(in);
    f32x4 A = in4[3 * p + 0];
    f32x4 B = in4[3 * p + 1];
    f32x4 C = in4[3 * p + 2];

    // element0 = {A0 A1 A2 A3 B0 B1}, element1 = {B2 B3 C0 C1 C2 C3}
    // Feature stage packed ACROSS ELEMENTS (no weights involved, no splats).
    f32x2 px0 = {A[0], B[2]}, py0 = {A[1], B[3]}, pz0 = {A[2], C[0]};
    f32x2 px1 = {A[3], C[1]}, py1 = {B[0], C[2]}, pz1 = {B[1], C[3]};

    f32x2 dx = px1 - px0;
    f32x2 dy = py1 - py0;
    f32x2 dz = pz1 - pz0;
    f32x2 sep_xy2 = fma2(dx, dx, dy * dy);
    f32x2 sep_r2  = fma2(dz, dz, sep_xy2);
    f32x2 inv_r2  = {__builtin_amdgcn_rcpf(sep_r2[0]),
                     __builtin_amdgcn_rcpf(sep_r2[1])};

    float oo[4];

    #pragma unroll
    for (int e = 0; e < 2; ++e) {
        // MLP stage packed ACROSS NEURON PAIRS (j, j+1).
        float zin[3] = {pz0[e], pz1[e], sep_xy2[e]};

        // Layer 1: [3] -> [10], leaky relu
        f32x2 acc1[5];
        #pragma unroll
        for (int jp = 0; jp < 5; ++jp) acc1[jp] = ldpair(b1 + 2 * jp);
        #pragma unroll
        for (int i = 0; i < 3; ++i) {
            f32x2 hs = {zin[i], zin[i]};
            #pragma unroll
            for (int jp = 0; jp < 5; ++jp)
                acc1[jp] = fma2(hs, ldpair(W1 + i * 10 + 2 * jp), acc1[jp]);
        }
        f32x2 h1[5];
        #pragma unroll
        for (int jp = 0; jp < 5; ++jp) h1[jp] = lrelu2(acc1[jp]);

        // Layer 2: [10] -> [10], tanh
        f32x2 acc2[5];
        #pragma unroll
        for (int jp = 0; jp < 5; ++jp) acc2[jp] = ldpair(b2 + 2 * jp);
        #pragma unroll
        for (int i = 0; i < 10; ++i) {
            float hv = h1[i >> 1][i & 1];
            f32x2 hs = {hv, hv};
            #pragma unroll
            for (int jp = 0; jp < 5; ++jp)
                acc2[jp] = fma2(hs, ldpair(W2 + i * 10 + 2 * jp), acc2[jp]);
        }
        f32x2 h2[5];
        #pragma unroll
        for (int jp = 0; jp < 5; ++jp) {
            f32x2 t;
            t[0] = tanh_fast(acc2[jp][0]);
            t[1] = tanh_fast(acc2[jp][1]);
            h2[jp] = t;
        }

        // Layer 3: [10] -> [10], leaky relu
        f32x2 acc3[5];
        #pragma unroll
        for (int jp = 0; jp < 5; ++jp) acc3[jp] = ldpair(b3 + 2 * jp);
        #pragma unroll
        for (int i = 0; i < 10; ++i) {
            float hv = h2[i >> 1][i & 1];
            f32x2 hs = {hv, hv};
            #pragma unroll
            for (int jp = 0; jp < 5; ++jp)
                acc3[jp] = fma2(hs, ldpair(W3 + i * 10 + 2 * jp), acc3[jp]);
        }
        f32x2 h3[5];
        #pragma unroll
        for (int jp = 0; jp < 5; ++jp) h3[jp] = lrelu2(acc3[jp]);

        // Layer 4: [10] -> [1]; h3 already paired, W4 contiguous pairs.
        f32x2 fp = {b4[0], 0.0f};
        #pragma unroll
        for (int ip = 0; ip < 5; ++ip)
            fp = fma2(h3[ip], ldpair(W4 + 2 * ip), fp);
        float f = fp[0] + fp[1];

        float s = f * inv_r2[e];
        oo[2 * e + 0] = s * dx[e];
        oo[2 * e + 1] = s * dy[e];
    }

    f32x4 o;
    o[0] = oo[0]; o[1] = oo[1]; o[2] = oo[2]; o[3] = oo[3];
    reinterpret_cast<f32x4*>(out)[p] = o;
}

extern "C" void kernel_launch(void* const* d_in, const int* in_sizes, int n_in,
                              void* d_out, int out_size, void* d_ws, size_t ws_size,
                              hipStream_t stream) {
    const float* in = (const float*)d_in[0];
    const float* W1 = (const float*)d_in[1];
    const float* b1 = (const float*)d_in[2];
    const float* W2 = (const float*)d_in[3];
    const float* b2 = (const float*)d_in[4];
    const float* W3 = (const float*)d_in[5];
    const float* b3 = (const float*)d_in[6];
    const float* W4 = (const float*)d_in[7];
    const float* b4 = (const float*)d_in[8];
    float* out = (float*)d_out;

    int npairs = out_size / 4;          // 2 elements (4 output floats) per thread
    int blocks = (npairs + 255) / 256;
    fused_mlp_kernel<<<blocks, 256, 0, stream>>>(
        in, W1, b1, W2, b2, W3, b3, W4, b4, out, npairs);
}